// Round 1
// 5780.770 us; speedup vs baseline: 1.6118x; 1.6118x over previous
//
#include <hip/hip_runtime.h>

#define D_MODEL 1024
#define D_INNER 2048
#define DT_RANK 64            // (1024+15)//16
#define D_STATE 16
#define NXP     96            // DT_RANK + 2*D_STATE
#define SEQL    2048
#define NLAYERS 2

// ---------------------------------------------------------------- embed
__global__ __launch_bounds__(256) void embed_k(const int* __restrict__ ids,
                                               const float* __restrict__ emb,
                                               float* __restrict__ x) {
    int l = blockIdx.x;
    int id = ids[l];
    const float* src = emb + (size_t)id * D_MODEL;
    float* dst = x + (size_t)l * D_MODEL;
    for (int d = threadIdx.x; d < D_MODEL; d += 256) dst[d] = src[d];
}

// ---------------------------------------------------------------- layernorm (one row per block)
__global__ __launch_bounds__(256) void ln_k(const float* __restrict__ x,
                                            const float* __restrict__ g,
                                            const float* __restrict__ b,
                                            float* __restrict__ out) {
    int l = blockIdx.x;
    const float* xr = x + (size_t)l * D_MODEL;
    float s = 0.f, s2 = 0.f;
    for (int d = threadIdx.x; d < D_MODEL; d += 256) {
        float v = xr[d];
        s += v; s2 += v * v;
    }
    __shared__ float red[2][4];
    for (int off = 32; off; off >>= 1) {
        s  += __shfl_down(s,  off);
        s2 += __shfl_down(s2, off);
    }
    int wid = threadIdx.x >> 6, lid = threadIdx.x & 63;
    if (lid == 0) { red[0][wid] = s; red[1][wid] = s2; }
    __syncthreads();
    float ts  = red[0][0] + red[0][1] + red[0][2] + red[0][3];
    float ts2 = red[1][0] + red[1][1] + red[1][2] + red[1][3];
    float mean = ts * (1.0f / D_MODEL);
    float var  = ts2 * (1.0f / D_MODEL) - mean * mean;
    float rstd = rsqrtf(var + 1e-5f);
    float* o = out + (size_t)l * D_MODEL;
    for (int d = threadIdx.x; d < D_MODEL; d += 256)
        o[d] = (xr[d] - mean) * rstd * g[d] + b[d];
}

// ---------------------------------------------------------------- bf16x3 MFMA NT GEMM
// C[M,N] = A[M,K] * B[N,K]^T, f32 in/out, bf16 split (hi+lo) inputs, f32 MFMA accumulate.
// Error per product ~2^-17 relative (vs f32's reassociation noise) — accuracy-safe.
// Tile: 128x128, BK=32, 256 threads = 4 waves of 64x64 output each.
// LDS: XOR-swizzled [128][32] bf16 tiles (hi & lo for A and B), double-buffered = 64 KB.
// Grid: blockIdx.x = M (fast) so the 16 M-blocks sharing one B (weight) panel run
// adjacently -> B fetched ~once through L2/L3 instead of 16x.

typedef short bf16x8 __attribute__((ext_vector_type(8)));
typedef float f32x4  __attribute__((ext_vector_type(4)));

// byte offset inside an 8 KB [128 rows][32 k] bf16 tile; bijective XOR swizzle:
// 16B chunk (r,q) -> spreads 8 consecutive rows over all 32 banks (slots 0,5,2,7,4,1,6,3)
__device__ __forceinline__ int swz(int r, int q) {
    return ((r << 6) + (q << 4)) ^ ((r & 7) << 4);
}

// round-to-nearest-even f32 -> bf16 (bit trick; inputs finite)
__device__ __forceinline__ void cvt_store16(char* __restrict__ hi, char* __restrict__ lo,
                                            const float4 v0, const float4 v1, int off) {
    float v[8] = {v0.x, v0.y, v0.z, v0.w, v1.x, v1.y, v1.z, v1.w};
    union { unsigned short us[8]; uint4 q4; } H, L;
#pragma unroll
    for (int i = 0; i < 8; i++) {
        unsigned u  = __float_as_uint(v[i]);
        unsigned ur = u + 0x7fffu + ((u >> 16) & 1u);
        unsigned short h = (unsigned short)(ur >> 16);
        float rest  = v[i] - __uint_as_float((unsigned)h << 16);
        unsigned u2  = __float_as_uint(rest);
        unsigned ur2 = u2 + 0x7fffu + ((u2 >> 16) & 1u);
        H.us[i] = h;
        L.us[i] = (unsigned short)(ur2 >> 16);
    }
    *(uint4*)(hi + off) = H.q4;
    *(uint4*)(lo + off) = L.q4;
}

// EPI: 0 = plain store, 1 = softplus(c + bias[n]), 2 = c + resid
template <int EPI>
__global__ __launch_bounds__(256, 2) void gemm_mfma(const float* __restrict__ A, int lda,
                                                    const float* __restrict__ B, int ldb,
                                                    float* __restrict__ C, int ldc,
                                                    int M, int N, int K,
                                                    const float* __restrict__ bias,
                                                    const float* __restrict__ resid) {
    // [buf][0=Ahi 1=Alo 2=Bhi 3=Blo][8KB]
    __shared__ char lds[2][4][8192];

    const int t    = threadIdx.x;
    const int m0   = blockIdx.x * 128;
    const int n0   = blockIdx.y * 128;
    const int lane = t & 63;
    const int w    = t >> 6;
    const int wm   = (w >> 1) * 64;        // wave's row offset in tile
    const int wn   = (w & 1) * 64;         // wave's col offset in tile
    const int rl   = lane & 15;
    const int kq   = lane >> 4;            // 16B chunk along k
    const int sr   = t >> 2;               // staging row 0..63 (and +64)
    const int sq   = t & 3;                // staging 16B chunk 0..3

    const float* Ar0 = A + (size_t)(m0 + sr) * lda + sq * 8;
    const float* Ar1 = Ar0 + (size_t)64 * lda;
    const int nr0 = n0 + sr, nr1 = n0 + sr + 64;
    const float* Br0 = B + (size_t)nr0 * ldb + sq * 8;
    const float* Br1 = B + (size_t)nr1 * ldb + sq * 8;
    const bool bv0 = (nr0 < N), bv1 = (nr1 < N);
    const int off0 = swz(sr, sq), off1 = swz(sr + 64, sq);

    f32x4 acc[4][4] = {};
    const float4 fz = {0.f, 0.f, 0.f, 0.f};
    float4 pa0, pa1, pa2, pa3, pb0, pb1, pb2, pb3;

    // prologue: load k-tile 0
    pa0 = *(const float4*)(Ar0);     pa1 = *(const float4*)(Ar0 + 4);
    pa2 = *(const float4*)(Ar1);     pa3 = *(const float4*)(Ar1 + 4);
    pb0 = bv0 ? *(const float4*)(Br0)     : fz;
    pb1 = bv0 ? *(const float4*)(Br0 + 4) : fz;
    pb2 = bv1 ? *(const float4*)(Br1)     : fz;
    pb3 = bv1 ? *(const float4*)(Br1 + 4) : fz;
    cvt_store16(lds[0][0], lds[0][1], pa0, pa1, off0);
    cvt_store16(lds[0][0], lds[0][1], pa2, pa3, off1);
    cvt_store16(lds[0][2], lds[0][3], pb0, pb1, off0);
    cvt_store16(lds[0][2], lds[0][3], pb2, pb3, off1);
    __syncthreads();

    const int nk = K >> 5;
    int buf = 0;
    for (int tk = 0; tk < nk; tk++) {
        // issue next-tile global loads BEFORE compute: HBM latency hides under MFMA
        if (tk + 1 < nk) {
            const int kb = (tk + 1) << 5;
            pa0 = *(const float4*)(Ar0 + kb);     pa1 = *(const float4*)(Ar0 + kb + 4);
            pa2 = *(const float4*)(Ar1 + kb);     pa3 = *(const float4*)(Ar1 + kb + 4);
            pb0 = bv0 ? *(const float4*)(Br0 + kb)     : fz;
            pb1 = bv0 ? *(const float4*)(Br0 + kb + 4) : fz;
            pb2 = bv1 ? *(const float4*)(Br1 + kb)     : fz;
            pb3 = bv1 ? *(const float4*)(Br1 + kb + 4) : fz;
        }

        {   // compute current buffer
            const char* Ahi = lds[buf][0];
            const char* Alo = lds[buf][1];
            const char* Bhi = lds[buf][2];
            const char* Blo = lds[buf][3];
            bf16x8 ah[4], al[4], bh[4], bl[4];
#pragma unroll
            for (int i = 0; i < 4; i++) {
                const int oa = swz(wm + i * 16 + rl, kq);
                ah[i] = *(const bf16x8*)(Ahi + oa);
                al[i] = *(const bf16x8*)(Alo + oa);
                const int ob = swz(wn + i * 16 + rl, kq);
                bh[i] = *(const bf16x8*)(Bhi + ob);
                bl[i] = *(const bf16x8*)(Blo + ob);
            }
#pragma unroll
            for (int i = 0; i < 4; i++)
#pragma unroll
                for (int j = 0; j < 4; j++) {
                    acc[i][j] = __builtin_amdgcn_mfma_f32_16x16x32_bf16(ah[i], bh[j], acc[i][j], 0, 0, 0);
                    acc[i][j] = __builtin_amdgcn_mfma_f32_16x16x32_bf16(ah[i], bl[j], acc[i][j], 0, 0, 0);
                    acc[i][j] = __builtin_amdgcn_mfma_f32_16x16x32_bf16(al[i], bh[j], acc[i][j], 0, 0, 0);
                }
        }

        if (tk + 1 < nk) {  // convert + write next tile into the other buffer
            const int nb = buf ^ 1;
            cvt_store16(lds[nb][0], lds[nb][1], pa0, pa1, off0);
            cvt_store16(lds[nb][0], lds[nb][1], pa2, pa3, off1);
            cvt_store16(lds[nb][2], lds[nb][3], pb0, pb1, off0);
            cvt_store16(lds[nb][2], lds[nb][3], pb2, pb3, off1);
        }
        __syncthreads();
        buf ^= 1;
    }

    // epilogue: C/D layout col = lane&15, row = (lane>>4)*4 + reg  (M=2048 -> no m guard)
#pragma unroll
    for (int i = 0; i < 4; i++) {
        const int mrow = m0 + wm + i * 16 + kq * 4;
#pragma unroll
        for (int j = 0; j < 4; j++) {
            const int n = n0 + wn + j * 16 + rl;
            if (n >= N) continue;
#pragma unroll
            for (int rj = 0; rj < 4; rj++) {
                const int m = mrow + rj;
                float c = acc[i][j][rj];
                if (EPI == 0) {
                    C[(size_t)m * ldc + n] = c;
                } else if (EPI == 1) {
                    float v = c + bias[n];
                    C[(size_t)m * ldc + n] = (v > 20.f) ? v : log1pf(expf(v));
                } else {
                    C[(size_t)m * ldc + n] = c + resid[(size_t)m * ldc + n];
                }
            }
        }
    }
}

// ---------------------------------------------------------------- causal depthwise conv(4) + SiLU
__global__ __launch_bounds__(256) void conv_silu_k(const float* __restrict__ xz,
                                                   const float* __restrict__ cw,
                                                   const float* __restrict__ cb,
                                                   float* __restrict__ xc) {
    int idx = blockIdx.x * 256 + threadIdx.x;       // SEQL * D_INNER threads
    int d = idx & (D_INNER - 1);
    int l = idx >> 11;
    float acc = cb[d];
#pragma unroll
    for (int k = 0; k < 4; k++) {
        int ls = l + k - 3;
        if (ls >= 0) acc += xz[(size_t)ls * (2 * D_INNER) + d] * cw[d * 4 + k];
    }
    acc = acc / (1.0f + expf(-acc));                // silu
    xc[(size_t)l * D_INNER + d] = acc;
}

// ---------------------------------------------------------------- selective scan
// 16 lanes per channel (one per state), 16 channels per 256-thread block.
__global__ __launch_bounds__(256) void scan_k(const float* __restrict__ dt,
                                              const float* __restrict__ xdbl,
                                              const float* __restrict__ xc,
                                              const float* __restrict__ xz,
                                              const float* __restrict__ A_log,
                                              const float* __restrict__ D_skip,
                                              float* __restrict__ y) {
    int t = threadIdx.x;
    int n = t & 15;
    int c = t >> 4;
    int d = blockIdx.x * 16 + c;
    float Ac = -expf(A_log[d * D_STATE + n]);
    float dsk = D_skip[d];
    float h = 0.0f;
    for (int l = 0; l < SEQL; l++) {
        float dtv = dt[(size_t)l * D_INNER + d];
        float xcv = xc[(size_t)l * D_INNER + d];
        float Bv  = xdbl[(size_t)l * NXP + DT_RANK + n];
        float Cv  = xdbl[(size_t)l * NXP + DT_RANK + D_STATE + n];
        h = expf(dtv * Ac) * h + dtv * Bv * xcv;
        float p = h * Cv;
#pragma unroll
        for (int off = 8; off; off >>= 1) p += __shfl_xor(p, off, 16);
        if (n == 0) {
            float zv = xz[(size_t)l * (2 * D_INNER) + D_INNER + d];
            float yv = (p + dsk * xcv) * (zv / (1.0f + expf(-zv)));
            y[(size_t)l * D_INNER + d] = yv;
        }
    }
}

// ---------------------------------------------------------------- launch
extern "C" void kernel_launch(void* const* d_in, const int* in_sizes, int n_in,
                              void* d_out, int out_size, void* d_ws, size_t ws_size,
                              hipStream_t stream) {
    const int*   ids       = (const int*)d_in[0];
    const float* emb       = (const float*)d_in[1];
    const float* ln_g      = (const float*)d_in[2];
    const float* ln_b      = (const float*)d_in[3];
    const float* in_proj_w = (const float*)d_in[4];
    const float* conv_w    = (const float*)d_in[5];
    const float* conv_b    = (const float*)d_in[6];
    const float* x_proj_w  = (const float*)d_in[7];
    const float* dt_proj_w = (const float*)d_in[8];
    const float* dt_proj_b = (const float*)d_in[9];
    const float* A_log     = (const float*)d_in[10];
    const float* D_skip    = (const float*)d_in[11];
    const float* out_proj_w= (const float*)d_in[12];
    const float* lnf_g     = (const float*)d_in[13];
    const float* lnf_b     = (const float*)d_in[14];
    const float* head_w    = (const float*)d_in[15];
    float* out = (float*)d_out;                        // f32 logits, per reference

    // workspace layout (f32), ~93 MB total; hy doubles as LN-out (SEQL*D_MODEL) and y (SEQL*D_INNER)
    float* ws   = (float*)d_ws;
    float* x    = ws;                                  // SEQL * D_MODEL
    float* hy   = x    + (size_t)SEQL * D_MODEL;       // SEQL * D_INNER (max of both uses)
    float* xz   = hy   + (size_t)SEQL * D_INNER;       // SEQL * 2*D_INNER
    float* xc   = xz   + (size_t)SEQL * 2 * D_INNER;   // SEQL * D_INNER
    float* xdbl = xc   + (size_t)SEQL * D_INNER;       // SEQL * NXP
    float* dt   = xdbl + (size_t)SEQL * NXP;           // SEQL * D_INNER

    embed_k<<<SEQL, 256, 0, stream>>>(ids, emb, x);

    for (int layer = 0; layer < NLAYERS; layer++) {
        ln_k<<<SEQL, 256, 0, stream>>>(x, ln_g + layer * D_MODEL, ln_b + layer * D_MODEL, hy);

        dim3 g1(SEQL / 128, (2 * D_INNER) / 128);      // M-fast: weight panel reuse in L2/L3
        gemm_mfma<0><<<g1, 256, 0, stream>>>(hy, D_MODEL,
                                             in_proj_w + (size_t)layer * 2 * D_INNER * D_MODEL, D_MODEL,
                                             xz, 2 * D_INNER, SEQL, 2 * D_INNER, D_MODEL,
                                             nullptr, nullptr);

        conv_silu_k<<<(SEQL * D_INNER) / 256, 256, 0, stream>>>(
            xz, conv_w + (size_t)layer * D_INNER * 4, conv_b + (size_t)layer * D_INNER, xc);

        dim3 g2(SEQL / 128, (NXP + 127) / 128);
        gemm_mfma<0><<<g2, 256, 0, stream>>>(xc, D_INNER,
                                             x_proj_w + (size_t)layer * NXP * D_INNER, D_INNER,
                                             xdbl, NXP, SEQL, NXP, D_INNER,
                                             nullptr, nullptr);

        dim3 g3(SEQL / 128, D_INNER / 128);
        gemm_mfma<1><<<g3, 256, 0, stream>>>(xdbl, NXP,
                                             dt_proj_w + (size_t)layer * D_INNER * DT_RANK, DT_RANK,
                                             dt, D_INNER, SEQL, D_INNER, DT_RANK,
                                             dt_proj_b + (size_t)layer * D_INNER, nullptr);

        scan_k<<<D_INNER / 16, 256, 0, stream>>>(dt, xdbl, xc, xz,
                                                 A_log + (size_t)layer * D_INNER * D_STATE,
                                                 D_skip + (size_t)layer * D_INNER, hy);

        dim3 g4(SEQL / 128, D_MODEL / 128);
        gemm_mfma<2><<<g4, 256, 0, stream>>>(hy, D_INNER,
                                             out_proj_w + (size_t)layer * D_MODEL * D_INNER, D_INNER,
                                             x, D_MODEL, SEQL, D_MODEL, D_INNER,
                                             nullptr, x);
    }

    ln_k<<<SEQL, 256, 0, stream>>>(x, lnf_g, lnf_b, hy);

    dim3 g5(SEQL / 128, 32000 / 128);
    gemm_mfma<0><<<g5, 256, 0, stream>>>(hy, D_MODEL, head_w, D_MODEL,
                                         out, 32000, SEQL, 32000, D_MODEL,
                                         nullptr, nullptr);
}

// Round 2
// 2828.450 us; speedup vs baseline: 3.2942x; 2.0438x over previous
//
#include <hip/hip_runtime.h>

#define D_MODEL 1024
#define D_INNER 2048
#define DT_RANK 64            // (1024+15)//16
#define D_STATE 16
#define NXP     96            // DT_RANK + 2*D_STATE
#define SEQL    2048
#define NLAYERS 2
#define NC      32            // scan chunks
#define LC      (SEQL / NC)   // 64 steps per chunk

// ---------------------------------------------------------------- embed
__global__ __launch_bounds__(256) void embed_k(const int* __restrict__ ids,
                                               const float* __restrict__ emb,
                                               float* __restrict__ x) {
    int l = blockIdx.x;
    int id = ids[l];
    const float* src = emb + (size_t)id * D_MODEL;
    float* dst = x + (size_t)l * D_MODEL;
    for (int d = threadIdx.x; d < D_MODEL; d += 256) dst[d] = src[d];
}

// ---------------------------------------------------------------- layernorm (one row per block)
__global__ __launch_bounds__(256) void ln_k(const float* __restrict__ x,
                                            const float* __restrict__ g,
                                            const float* __restrict__ b,
                                            float* __restrict__ out) {
    int l = blockIdx.x;
    const float* xr = x + (size_t)l * D_MODEL;
    float s = 0.f, s2 = 0.f;
    for (int d = threadIdx.x; d < D_MODEL; d += 256) {
        float v = xr[d];
        s += v; s2 += v * v;
    }
    __shared__ float red[2][4];
    for (int off = 32; off; off >>= 1) {
        s  += __shfl_down(s,  off);
        s2 += __shfl_down(s2, off);
    }
    int wid = threadIdx.x >> 6, lid = threadIdx.x & 63;
    if (lid == 0) { red[0][wid] = s; red[1][wid] = s2; }
    __syncthreads();
    float ts  = red[0][0] + red[0][1] + red[0][2] + red[0][3];
    float ts2 = red[1][0] + red[1][1] + red[1][2] + red[1][3];
    float mean = ts * (1.0f / D_MODEL);
    float var  = ts2 * (1.0f / D_MODEL) - mean * mean;
    float rstd = rsqrtf(var + 1e-5f);
    float* o = out + (size_t)l * D_MODEL;
    for (int d = threadIdx.x; d < D_MODEL; d += 256)
        o[d] = (xr[d] - mean) * rstd * g[d] + b[d];
}

// ---------------------------------------------------------------- bf16x3 MFMA NT GEMM
// C[M,N] = A[M,K] * B[N,K]^T, f32 in/out, bf16 split (hi+lo) inputs, f32 MFMA accumulate.
// Tile: 128x128, BK=32, 256 threads = 4 waves of 64x64 output each.
// LDS: XOR-swizzled [128][32] bf16 tiles (hi & lo for A and B), double-buffered = 64 KB.
// Grid: blockIdx.x = M (fast) so the 16 M-blocks sharing one B (weight) panel run
// adjacently -> B fetched ~once through L2/L3 instead of 16x.

typedef short bf16x8 __attribute__((ext_vector_type(8)));
typedef float f32x4  __attribute__((ext_vector_type(4)));

__device__ __forceinline__ int swz(int r, int q) {
    return ((r << 6) + (q << 4)) ^ ((r & 7) << 4);
}

// round-to-nearest-even f32 -> bf16 split (hi + residual)
__device__ __forceinline__ void cvt_store16(char* __restrict__ hi, char* __restrict__ lo,
                                            const float4 v0, const float4 v1, int off) {
    float v[8] = {v0.x, v0.y, v0.z, v0.w, v1.x, v1.y, v1.z, v1.w};
    union { unsigned short us[8]; uint4 q4; } H, L;
#pragma unroll
    for (int i = 0; i < 8; i++) {
        unsigned u  = __float_as_uint(v[i]);
        unsigned ur = u + 0x7fffu + ((u >> 16) & 1u);
        unsigned short h = (unsigned short)(ur >> 16);
        float rest  = v[i] - __uint_as_float((unsigned)h << 16);
        unsigned u2  = __float_as_uint(rest);
        unsigned ur2 = u2 + 0x7fffu + ((u2 >> 16) & 1u);
        H.us[i] = h;
        L.us[i] = (unsigned short)(ur2 >> 16);
    }
    *(uint4*)(hi + off) = H.q4;
    *(uint4*)(lo + off) = L.q4;
}

// EPI: 0 = plain store, 1 = softplus(c + bias[n]), 2 = c + resid
template <int EPI>
__global__ __launch_bounds__(256, 2) void gemm_mfma(const float* __restrict__ A, int lda,
                                                    const float* __restrict__ B, int ldb,
                                                    float* __restrict__ C, int ldc,
                                                    int M, int N, int K,
                                                    const float* __restrict__ bias,
                                                    const float* __restrict__ resid) {
    __shared__ char lds[2][4][8192];

    const int t    = threadIdx.x;
    const int m0   = blockIdx.x * 128;
    const int n0   = blockIdx.y * 128;
    const int lane = t & 63;
    const int w    = t >> 6;
    const int wm   = (w >> 1) * 64;
    const int wn   = (w & 1) * 64;
    const int rl   = lane & 15;
    const int kq   = lane >> 4;
    const int sr   = t >> 2;
    const int sq   = t & 3;

    const float* Ar0 = A + (size_t)(m0 + sr) * lda + sq * 8;
    const float* Ar1 = Ar0 + (size_t)64 * lda;
    const int nr0 = n0 + sr, nr1 = n0 + sr + 64;
    const float* Br0 = B + (size_t)nr0 * ldb + sq * 8;
    const float* Br1 = B + (size_t)nr1 * ldb + sq * 8;
    const bool bv0 = (nr0 < N), bv1 = (nr1 < N);
    const int off0 = swz(sr, sq), off1 = swz(sr + 64, sq);

    f32x4 acc[4][4] = {};
    const float4 fz = {0.f, 0.f, 0.f, 0.f};
    float4 pa0, pa1, pa2, pa3, pb0, pb1, pb2, pb3;

    pa0 = *(const float4*)(Ar0);     pa1 = *(const float4*)(Ar0 + 4);
    pa2 = *(const float4*)(Ar1);     pa3 = *(const float4*)(Ar1 + 4);
    pb0 = bv0 ? *(const float4*)(Br0)     : fz;
    pb1 = bv0 ? *(const float4*)(Br0 + 4) : fz;
    pb2 = bv1 ? *(const float4*)(Br1)     : fz;
    pb3 = bv1 ? *(const float4*)(Br1 + 4) : fz;
    cvt_store16(lds[0][0], lds[0][1], pa0, pa1, off0);
    cvt_store16(lds[0][0], lds[0][1], pa2, pa3, off1);
    cvt_store16(lds[0][2], lds[0][3], pb0, pb1, off0);
    cvt_store16(lds[0][2], lds[0][3], pb2, pb3, off1);
    __syncthreads();

    const int nk = K >> 5;
    int buf = 0;
    for (int tk = 0; tk < nk; tk++) {
        if (tk + 1 < nk) {
            const int kb = (tk + 1) << 5;
            pa0 = *(const float4*)(Ar0 + kb);     pa1 = *(const float4*)(Ar0 + kb + 4);
            pa2 = *(const float4*)(Ar1 + kb);     pa3 = *(const float4*)(Ar1 + kb + 4);
            pb0 = bv0 ? *(const float4*)(Br0 + kb)     : fz;
            pb1 = bv0 ? *(const float4*)(Br0 + kb + 4) : fz;
            pb2 = bv1 ? *(const float4*)(Br1 + kb)     : fz;
            pb3 = bv1 ? *(const float4*)(Br1 + kb + 4) : fz;
        }

        {
            const char* Ahi = lds[buf][0];
            const char* Alo = lds[buf][1];
            const char* Bhi = lds[buf][2];
            const char* Blo = lds[buf][3];
            bf16x8 ah[4], al[4], bh[4], bl[4];
#pragma unroll
            for (int i = 0; i < 4; i++) {
                const int oa = swz(wm + i * 16 + rl, kq);
                ah[i] = *(const bf16x8*)(Ahi + oa);
                al[i] = *(const bf16x8*)(Alo + oa);
                const int ob = swz(wn + i * 16 + rl, kq);
                bh[i] = *(const bf16x8*)(Bhi + ob);
                bl[i] = *(const bf16x8*)(Blo + ob);
            }
#pragma unroll
            for (int i = 0; i < 4; i++)
#pragma unroll
                for (int j = 0; j < 4; j++) {
                    acc[i][j] = __builtin_amdgcn_mfma_f32_16x16x32_bf16(ah[i], bh[j], acc[i][j], 0, 0, 0);
                    acc[i][j] = __builtin_amdgcn_mfma_f32_16x16x32_bf16(ah[i], bl[j], acc[i][j], 0, 0, 0);
                    acc[i][j] = __builtin_amdgcn_mfma_f32_16x16x32_bf16(al[i], bh[j], acc[i][j], 0, 0, 0);
                }
        }

        if (tk + 1 < nk) {
            const int nb = buf ^ 1;
            cvt_store16(lds[nb][0], lds[nb][1], pa0, pa1, off0);
            cvt_store16(lds[nb][0], lds[nb][1], pa2, pa3, off1);
            cvt_store16(lds[nb][2], lds[nb][3], pb0, pb1, off0);
            cvt_store16(lds[nb][2], lds[nb][3], pb2, pb3, off1);
        }
        __syncthreads();
        buf ^= 1;
    }

#pragma unroll
    for (int i = 0; i < 4; i++) {
        const int mrow = m0 + wm + i * 16 + kq * 4;
#pragma unroll
        for (int j = 0; j < 4; j++) {
            const int n = n0 + wn + j * 16 + rl;
            if (n >= N) continue;
#pragma unroll
            for (int rj = 0; rj < 4; rj++) {
                const int m = mrow + rj;
                float c = acc[i][j][rj];
                if (EPI == 0) {
                    C[(size_t)m * ldc + n] = c;
                } else if (EPI == 1) {
                    float v = c + bias[n];
                    C[(size_t)m * ldc + n] = (v > 20.f) ? v : log1pf(expf(v));
                } else {
                    C[(size_t)m * ldc + n] = c + resid[(size_t)m * ldc + n];
                }
            }
        }
    }
}

// ---------------------------------------------------------------- causal depthwise conv(4) + SiLU
__global__ __launch_bounds__(256) void conv_silu_k(const float* __restrict__ xz,
                                                   const float* __restrict__ cw,
                                                   const float* __restrict__ cb,
                                                   float* __restrict__ xc) {
    int idx = blockIdx.x * 256 + threadIdx.x;
    int d = idx & (D_INNER - 1);
    int l = idx >> 11;
    float acc = cb[d];
#pragma unroll
    for (int k = 0; k < 4; k++) {
        int ls = l + k - 3;
        if (ls >= 0) acc += xz[(size_t)ls * (2 * D_INNER) + d] * cw[d * 4 + k];
    }
    acc = acc / (1.0f + expf(-acc));
    xc[(size_t)l * D_INNER + d] = acc;
}

// ---------------------------------------------------------------- chunked selective scan
// h[l] = a[l] h[l-1] + b[l] is associative under (a1,b1)∘(a2,b2)=(a1a2, a2b1+b2).
// Pass 1: per (d,n,chunk) local scan from h=0, emit (prod a, final h).  32x parallelism.
// Pass 2: serial combine over NC=32 chunk carries -> per-chunk starting state.
// Pass 3: re-run local scan seeded with h_start, emit y (shfl-reduce over 16 states).
// a = exp(dt*A) in (0,1] (softplus dt>=0, A<0) -> recombination is contraction-stable.

__global__ __launch_bounds__(256) void scan_p1(const float* __restrict__ dt,
                                               const float* __restrict__ xdbl,
                                               const float* __restrict__ xc,
                                               const float* __restrict__ A_log,
                                               float* __restrict__ Pbuf,
                                               float* __restrict__ Hbuf) {
    int t = threadIdx.x;
    int n = t & 15;
    int d = blockIdx.x * 16 + (t >> 4);
    int ch = blockIdx.y;
    int l0 = ch * LC;
    float Ac = -expf(A_log[d * D_STATE + n]);
    float h = 0.f, P = 1.f;
#pragma unroll 4
    for (int i = 0; i < LC; i++) {
        int l = l0 + i;
        float dtv = dt[(size_t)l * D_INNER + d];
        float xcv = xc[(size_t)l * D_INNER + d];
        float Bv  = xdbl[(size_t)l * NXP + DT_RANK + n];
        float a = expf(dtv * Ac);
        h = a * h + dtv * Bv * xcv;
        P *= a;
    }
    int idx = ch * (D_INNER * D_STATE) + d * D_STATE + n;
    Pbuf[idx] = P;
    Hbuf[idx] = h;
}

__global__ __launch_bounds__(256) void scan_p2(const float* __restrict__ Pbuf,
                                               const float* __restrict__ Hbuf,
                                               float* __restrict__ HSbuf) {
    int tid = blockIdx.x * 256 + threadIdx.x;      // 32768 threads, one per (d,n)
    float hs = 0.f;
#pragma unroll
    for (int ch = 0; ch < NC; ch++) {
        int idx = ch * (D_INNER * D_STATE) + tid;
        HSbuf[idx] = hs;
        hs = Pbuf[idx] * hs + Hbuf[idx];
    }
}

__global__ __launch_bounds__(256) void scan_p3(const float* __restrict__ dt,
                                               const float* __restrict__ xdbl,
                                               const float* __restrict__ xc,
                                               const float* __restrict__ xz,
                                               const float* __restrict__ A_log,
                                               const float* __restrict__ D_skip,
                                               const float* __restrict__ HSbuf,
                                               float* __restrict__ y) {
    int t = threadIdx.x;
    int n = t & 15;
    int d = blockIdx.x * 16 + (t >> 4);
    int ch = blockIdx.y;
    int l0 = ch * LC;
    float Ac = -expf(A_log[d * D_STATE + n]);
    float dsk = D_skip[d];
    float h = HSbuf[ch * (D_INNER * D_STATE) + d * D_STATE + n];
    for (int i = 0; i < LC; i++) {
        int l = l0 + i;
        float dtv = dt[(size_t)l * D_INNER + d];
        float xcv = xc[(size_t)l * D_INNER + d];
        float Bv  = xdbl[(size_t)l * NXP + DT_RANK + n];
        float Cv  = xdbl[(size_t)l * NXP + DT_RANK + D_STATE + n];
        float a = expf(dtv * Ac);
        h = a * h + dtv * Bv * xcv;
        float p = h * Cv;
#pragma unroll
        for (int off = 8; off; off >>= 1) p += __shfl_xor(p, off, 16);
        if (n == 0) {
            float zv = xz[(size_t)l * (2 * D_INNER) + D_INNER + d];
            float yv = (p + dsk * xcv) * (zv / (1.0f + expf(-zv)));
            y[(size_t)l * D_INNER + d] = yv;
        }
    }
}

// ---------------------------------------------------------------- launch
extern "C" void kernel_launch(void* const* d_in, const int* in_sizes, int n_in,
                              void* d_out, int out_size, void* d_ws, size_t ws_size,
                              hipStream_t stream) {
    const int*   ids       = (const int*)d_in[0];
    const float* emb       = (const float*)d_in[1];
    const float* ln_g      = (const float*)d_in[2];
    const float* ln_b      = (const float*)d_in[3];
    const float* in_proj_w = (const float*)d_in[4];
    const float* conv_w    = (const float*)d_in[5];
    const float* conv_b    = (const float*)d_in[6];
    const float* x_proj_w  = (const float*)d_in[7];
    const float* dt_proj_w = (const float*)d_in[8];
    const float* dt_proj_b = (const float*)d_in[9];
    const float* A_log     = (const float*)d_in[10];
    const float* D_skip    = (const float*)d_in[11];
    const float* out_proj_w= (const float*)d_in[12];
    const float* lnf_g     = (const float*)d_in[13];
    const float* lnf_b     = (const float*)d_in[14];
    const float* head_w    = (const float*)d_in[15];
    float* out = (float*)d_out;

    // workspace layout (f32); hy doubles as LN-out (SEQL*D_MODEL) and y (SEQL*D_INNER)
    float* ws   = (float*)d_ws;
    float* x    = ws;
    float* hy   = x    + (size_t)SEQL * D_MODEL;
    float* xz   = hy   + (size_t)SEQL * D_INNER;
    float* xc   = xz   + (size_t)SEQL * 2 * D_INNER;
    float* xdbl = xc   + (size_t)SEQL * D_INNER;
    float* dt   = xdbl + (size_t)SEQL * NXP;

    // scan chunk-carry scratch lives in `out` (dead until the final head GEMM):
    // 3 x NC x 32768 floats = 12 MB of the 262 MB logits buffer.
    float* Pbuf  = out;
    float* Hbuf  = Pbuf + (size_t)NC * D_INNER * D_STATE;
    float* HSbuf = Hbuf + (size_t)NC * D_INNER * D_STATE;

    embed_k<<<SEQL, 256, 0, stream>>>(ids, emb, x);

    for (int layer = 0; layer < NLAYERS; layer++) {
        ln_k<<<SEQL, 256, 0, stream>>>(x, ln_g + layer * D_MODEL, ln_b + layer * D_MODEL, hy);

        dim3 g1(SEQL / 128, (2 * D_INNER) / 128);
        gemm_mfma<0><<<g1, 256, 0, stream>>>(hy, D_MODEL,
                                             in_proj_w + (size_t)layer * 2 * D_INNER * D_MODEL, D_MODEL,
                                             xz, 2 * D_INNER, SEQL, 2 * D_INNER, D_MODEL,
                                             nullptr, nullptr);

        conv_silu_k<<<(SEQL * D_INNER) / 256, 256, 0, stream>>>(
            xz, conv_w + (size_t)layer * D_INNER * 4, conv_b + (size_t)layer * D_INNER, xc);

        dim3 g2(SEQL / 128, (NXP + 127) / 128);
        gemm_mfma<0><<<g2, 256, 0, stream>>>(xc, D_INNER,
                                             x_proj_w + (size_t)layer * NXP * D_INNER, D_INNER,
                                             xdbl, NXP, SEQL, NXP, D_INNER,
                                             nullptr, nullptr);

        dim3 g3(SEQL / 128, D_INNER / 128);
        gemm_mfma<1><<<g3, 256, 0, stream>>>(xdbl, NXP,
                                             dt_proj_w + (size_t)layer * D_INNER * DT_RANK, DT_RANK,
                                             dt, D_INNER, SEQL, D_INNER, DT_RANK,
                                             dt_proj_b + (size_t)layer * D_INNER, nullptr);

        dim3 gs(D_INNER / 16, NC);
        scan_p1<<<gs, 256, 0, stream>>>(dt, xdbl, xc,
                                        A_log + (size_t)layer * D_INNER * D_STATE, Pbuf, Hbuf);
        scan_p2<<<(D_INNER * D_STATE) / 256, 256, 0, stream>>>(Pbuf, Hbuf, HSbuf);
        scan_p3<<<gs, 256, 0, stream>>>(dt, xdbl, xc, xz,
                                        A_log + (size_t)layer * D_INNER * D_STATE,
                                        D_skip + (size_t)layer * D_INNER, HSbuf, hy);

        dim3 g4(SEQL / 128, D_MODEL / 128);
        gemm_mfma<2><<<g4, 256, 0, stream>>>(hy, D_INNER,
                                             out_proj_w + (size_t)layer * D_MODEL * D_INNER, D_INNER,
                                             x, D_MODEL, SEQL, D_MODEL, D_INNER,
                                             nullptr, x);
    }

    ln_k<<<SEQL, 256, 0, stream>>>(x, lnf_g, lnf_b, hy);

    dim3 g5(SEQL / 128, 32000 / 128);
    gemm_mfma<0><<<g5, 256, 0, stream>>>(hy, D_MODEL, head_w, D_MODEL,
                                         out, 32000, SEQL, 32000, D_MODEL,
                                         nullptr, nullptr);
}

// Round 3
// 1622.339 us; speedup vs baseline: 5.7432x; 1.7434x over previous
//
#include <hip/hip_runtime.h>

#define D_MODEL 1024
#define D_INNER 2048
#define DT_RANK 64            // (1024+15)//16
#define D_STATE 16
#define NXP     96            // DT_RANK + 2*D_STATE
#define SEQL    2048
#define NLAYERS 2
#define NC      32            // scan chunks
#define LC      (SEQL / NC)   // 64 steps per chunk
#define VOCAB   32000

// ---------------------------------------------------------------- embed
__global__ __launch_bounds__(256) void embed_k(const int* __restrict__ ids,
                                               const float* __restrict__ emb,
                                               float* __restrict__ x) {
    int l = blockIdx.x;
    int id = ids[l];
    const float* src = emb + (size_t)id * D_MODEL;
    float* dst = x + (size_t)l * D_MODEL;
    for (int d = threadIdx.x; d < D_MODEL; d += 256) dst[d] = src[d];
}

// ---------------------------------------------------------------- layernorm (one row per block)
__global__ __launch_bounds__(256) void ln_k(const float* __restrict__ x,
                                            const float* __restrict__ g,
                                            const float* __restrict__ b,
                                            float* __restrict__ out) {
    int l = blockIdx.x;
    const float* xr = x + (size_t)l * D_MODEL;
    float s = 0.f, s2 = 0.f;
    for (int d = threadIdx.x; d < D_MODEL; d += 256) {
        float v = xr[d];
        s += v; s2 += v * v;
    }
    __shared__ float red[2][4];
    for (int off = 32; off; off >>= 1) {
        s  += __shfl_down(s,  off);
        s2 += __shfl_down(s2, off);
    }
    int wid = threadIdx.x >> 6, lid = threadIdx.x & 63;
    if (lid == 0) { red[0][wid] = s; red[1][wid] = s2; }
    __syncthreads();
    float ts  = red[0][0] + red[0][1] + red[0][2] + red[0][3];
    float ts2 = red[1][0] + red[1][1] + red[1][2] + red[1][3];
    float mean = ts * (1.0f / D_MODEL);
    float var  = ts2 * (1.0f / D_MODEL) - mean * mean;
    float rstd = rsqrtf(var + 1e-5f);
    float* o = out + (size_t)l * D_MODEL;
    for (int d = threadIdx.x; d < D_MODEL; d += 256)
        o[d] = (xr[d] - mean) * rstd * g[d] + b[d];
}

// ---------------------------------------------------------------- bf16x3 split helpers
typedef short bf16x8 __attribute__((ext_vector_type(8)));
typedef float f32x4  __attribute__((ext_vector_type(4)));

// byte offset of a 16B chunk inside an 8 KB [128 rows][32 k] bf16 tile (bijective XOR swizzle)
__device__ __forceinline__ int swz(int r, int q) {
    return ((r << 6) + (q << 4)) ^ ((r & 7) << 4);
}

// RNE f32 -> bf16 split (hi + residual lo), 8 elems
__device__ __forceinline__ void split8(const float4 v0, const float4 v1, uint4& Ho, uint4& Lo) {
    float v[8] = {v0.x, v0.y, v0.z, v0.w, v1.x, v1.y, v1.z, v1.w};
    union { unsigned short us[8]; uint4 q4; } H, L;
#pragma unroll
    for (int i = 0; i < 8; i++) {
        unsigned u  = __float_as_uint(v[i]);
        unsigned ur = u + 0x7fffu + ((u >> 16) & 1u);
        unsigned short h = (unsigned short)(ur >> 16);
        float rest  = v[i] - __uint_as_float((unsigned)h << 16);
        unsigned u2  = __float_as_uint(rest);
        unsigned ur2 = u2 + 0x7fffu + ((u2 >> 16) & 1u);
        H.us[i] = h;
        L.us[i] = (unsigned short)(ur2 >> 16);
    }
    Ho = H.q4; Lo = L.q4;
}

__device__ __forceinline__ void cvt_store16(char* __restrict__ hi, char* __restrict__ lo,
                                            const float4 v0, const float4 v1, int off) {
    uint4 H, L;
    split8(v0, v1, H, L);
    *(uint4*)(hi + off) = H;
    *(uint4*)(lo + off) = L;
}

// ---------------------------------------------------------------- pre-convert pass
// f32 [R x ld] row-major -> tile-blocked bf16 hi/lo, [rblk][kblk][8KB tile], swizzle
// baked into the GLOBAL layout so GEMM can global_load_lds linearly (m173 pattern).
// Rows >= R are zero-padded. grid = (K/32, Rpad/128), 256 threads.
__global__ __launch_bounds__(256) void cvt_k(const float* __restrict__ src, int ld, int R,
                                             short* __restrict__ hi, short* __restrict__ lo) {
    int kblk = blockIdx.x, rblk = blockIdx.y;
    int nkt = gridDim.x;
    size_t tileB = ((size_t)rblk * nkt + kblk) * 8192;
    char* hB = (char*)hi + tileB;
    char* lB = (char*)lo + tileB;
    int t = threadIdx.x;
#pragma unroll
    for (int half = 0; half < 2; half++) {
        int c = t + half * 256;          // chunk 0..511
        int r = c >> 2, q = c & 3;
        int gr = rblk * 128 + r;
        float4 v0 = {0.f,0.f,0.f,0.f}, v1 = {0.f,0.f,0.f,0.f};
        if (gr < R) {
            const float* p = src + (size_t)gr * ld + kblk * 32 + q * 8;
            v0 = *(const float4*)p;
            v1 = *(const float4*)(p + 4);
        }
        uint4 H, L;
        split8(v0, v1, H, L);
        int off = swz(r, q);
        *(uint4*)(hB + off) = H;
        *(uint4*)(lB + off) = L;
    }
}

// ---------------------------------------------------------------- async global->LDS
typedef const void __attribute__((address_space(1)))* gas_ptr;
typedef void __attribute__((address_space(3)))* las_ptr;
__device__ __forceinline__ void gload16(const void* g, void* l) {
    __builtin_amdgcn_global_load_lds((gas_ptr)g, (las_ptr)l, 16, 0, 0);
}

// ---------------------------------------------------------------- pre-converted MFMA GEMM
// Inputs are tile-blocked swizzled bf16 hi/lo (from cvt_k). m97 structure:
// global_load_lds staging (linear LDS <- pre-swizzled global), ds_read_b128, 48 MFMA/K-tile.
// C[M,N] = A*B^T (f32 out). grid = (M/128, Npad/128). EPI as before.
template <int EPI>
__global__ __launch_bounds__(256, 2) void gemm_pre(const short* __restrict__ Ahi, const short* __restrict__ Alo,
                                                   const short* __restrict__ Bhi, const short* __restrict__ Blo,
                                                   float* __restrict__ C, int ldc, int Nvalid, int K,
                                                   const float* __restrict__ bias,
                                                   const float* __restrict__ resid) {
    __shared__ char lds[2][4][8192];

    const int t    = threadIdx.x;
    const int lane = t & 63;
    const int w    = t >> 6;
    const int wm   = (w >> 1) * 64;
    const int wn   = (w & 1) * 64;
    const int rl   = lane & 15;
    const int kq   = lane >> 4;
    const int nkt  = K >> 5;

    const size_t aT = (size_t)blockIdx.x * nkt * 8192;   // bytes
    const size_t bT = (size_t)blockIdx.y * nkt * 8192;
    const char* Ah = (const char*)Ahi + aT;
    const char* Al = (const char*)Alo + aT;
    const char* Bh = (const char*)Bhi + bT;
    const char* Bl = (const char*)Blo + bT;

    const int o  = t * 16;            // 0..4095, = w*1024 + lane*16
    const int wb = w << 10;           // wave-uniform LDS base offset

    f32x4 acc[4][4] = {};

#define STAGE(BUF, KT)                                                          \
    {                                                                           \
        size_t kb = (size_t)(KT) * 8192;                                        \
        gload16(Ah + kb + o,        &lds[BUF][0][wb]);                          \
        gload16(Ah + kb + 4096 + o, &lds[BUF][0][wb + 4096]);                   \
        gload16(Al + kb + o,        &lds[BUF][1][wb]);                          \
        gload16(Al + kb + 4096 + o, &lds[BUF][1][wb + 4096]);                   \
        gload16(Bh + kb + o,        &lds[BUF][2][wb]);                          \
        gload16(Bh + kb + 4096 + o, &lds[BUF][2][wb + 4096]);                   \
        gload16(Bl + kb + o,        &lds[BUF][3][wb]);                          \
        gload16(Bl + kb + 4096 + o, &lds[BUF][3][wb + 4096]);                   \
    }

    STAGE(0, 0);
    __syncthreads();

    int buf = 0;
    for (int kt = 0; kt < nkt; kt++) {
        if (kt + 1 < nkt) STAGE(buf ^ 1, kt + 1);

        const char* Ahl = lds[buf][0];
        const char* All = lds[buf][1];
        const char* Bhl = lds[buf][2];
        const char* Bll = lds[buf][3];
        bf16x8 ah[4], al[4], bh[4], bl[4];
#pragma unroll
        for (int i = 0; i < 4; i++) {
            const int oa = swz(wm + i * 16 + rl, kq);
            ah[i] = *(const bf16x8*)(Ahl + oa);
            al[i] = *(const bf16x8*)(All + oa);
            const int ob = swz(wn + i * 16 + rl, kq);
            bh[i] = *(const bf16x8*)(Bhl + ob);
            bl[i] = *(const bf16x8*)(Bll + ob);
        }
#pragma unroll
        for (int i = 0; i < 4; i++)
#pragma unroll
            for (int j = 0; j < 4; j++) {
                acc[i][j] = __builtin_amdgcn_mfma_f32_16x16x32_bf16(ah[i], bh[j], acc[i][j], 0, 0, 0);
                acc[i][j] = __builtin_amdgcn_mfma_f32_16x16x32_bf16(ah[i], bl[j], acc[i][j], 0, 0, 0);
                acc[i][j] = __builtin_amdgcn_mfma_f32_16x16x32_bf16(al[i], bh[j], acc[i][j], 0, 0, 0);
            }
        __syncthreads();
        buf ^= 1;
    }
#undef STAGE

#pragma unroll
    for (int i = 0; i < 4; i++) {
        const int mrow = blockIdx.x * 128 + wm + i * 16 + kq * 4;
#pragma unroll
        for (int j = 0; j < 4; j++) {
            const int n = blockIdx.y * 128 + wn + j * 16 + rl;
            if (n >= Nvalid) continue;
#pragma unroll
            for (int rj = 0; rj < 4; rj++) {
                const int m = mrow + rj;
                float c = acc[i][j][rj];
                if (EPI == 0) {
                    C[(size_t)m * ldc + n] = c;
                } else if (EPI == 1) {
                    float v = c + bias[n];
                    C[(size_t)m * ldc + n] = (v > 20.f) ? v : log1pf(expf(v));
                } else {
                    C[(size_t)m * ldc + n] = c + resid[(size_t)m * ldc + n];
                }
            }
        }
    }
}

// ---------------------------------------------------------------- fallback GEMM (in-loop cvt)
template <int EPI>
__global__ __launch_bounds__(256, 2) void gemm_mfma(const float* __restrict__ A, int lda,
                                                    const float* __restrict__ B, int ldb,
                                                    float* __restrict__ C, int ldc,
                                                    int M, int N, int K,
                                                    const float* __restrict__ bias,
                                                    const float* __restrict__ resid) {
    __shared__ char lds[2][4][8192];

    const int t    = threadIdx.x;
    const int m0   = blockIdx.x * 128;
    const int n0   = blockIdx.y * 128;
    const int lane = t & 63;
    const int w    = t >> 6;
    const int wm   = (w >> 1) * 64;
    const int wn   = (w & 1) * 64;
    const int rl   = lane & 15;
    const int kq   = lane >> 4;
    const int sr   = t >> 2;
    const int sq   = t & 3;

    const float* Ar0 = A + (size_t)(m0 + sr) * lda + sq * 8;
    const float* Ar1 = Ar0 + (size_t)64 * lda;
    const int nr0 = n0 + sr, nr1 = n0 + sr + 64;
    const float* Br0 = B + (size_t)nr0 * ldb + sq * 8;
    const float* Br1 = B + (size_t)nr1 * ldb + sq * 8;
    const bool bv0 = (nr0 < N), bv1 = (nr1 < N);
    const int off0 = swz(sr, sq), off1 = swz(sr + 64, sq);

    f32x4 acc[4][4] = {};
    const float4 fz = {0.f, 0.f, 0.f, 0.f};
    float4 pa0, pa1, pa2, pa3, pb0, pb1, pb2, pb3;

    pa0 = *(const float4*)(Ar0);     pa1 = *(const float4*)(Ar0 + 4);
    pa2 = *(const float4*)(Ar1);     pa3 = *(const float4*)(Ar1 + 4);
    pb0 = bv0 ? *(const float4*)(Br0)     : fz;
    pb1 = bv0 ? *(const float4*)(Br0 + 4) : fz;
    pb2 = bv1 ? *(const float4*)(Br1)     : fz;
    pb3 = bv1 ? *(const float4*)(Br1 + 4) : fz;
    cvt_store16(lds[0][0], lds[0][1], pa0, pa1, off0);
    cvt_store16(lds[0][0], lds[0][1], pa2, pa3, off1);
    cvt_store16(lds[0][2], lds[0][3], pb0, pb1, off0);
    cvt_store16(lds[0][2], lds[0][3], pb2, pb3, off1);
    __syncthreads();

    const int nk = K >> 5;
    int buf = 0;
    for (int tk = 0; tk < nk; tk++) {
        if (tk + 1 < nk) {
            const int kb = (tk + 1) << 5;
            pa0 = *(const float4*)(Ar0 + kb);     pa1 = *(const float4*)(Ar0 + kb + 4);
            pa2 = *(const float4*)(Ar1 + kb);     pa3 = *(const float4*)(Ar1 + kb + 4);
            pb0 = bv0 ? *(const float4*)(Br0 + kb)     : fz;
            pb1 = bv0 ? *(const float4*)(Br0 + kb + 4) : fz;
            pb2 = bv1 ? *(const float4*)(Br1 + kb)     : fz;
            pb3 = bv1 ? *(const float4*)(Br1 + kb + 4) : fz;
        }
        {
            const char* Ahi = lds[buf][0];
            const char* Alo = lds[buf][1];
            const char* Bhi = lds[buf][2];
            const char* Blo = lds[buf][3];
            bf16x8 ah[4], al[4], bh[4], bl[4];
#pragma unroll
            for (int i = 0; i < 4; i++) {
                const int oa = swz(wm + i * 16 + rl, kq);
                ah[i] = *(const bf16x8*)(Ahi + oa);
                al[i] = *(const bf16x8*)(Alo + oa);
                const int ob = swz(wn + i * 16 + rl, kq);
                bh[i] = *(const bf16x8*)(Bhi + ob);
                bl[i] = *(const bf16x8*)(Blo + ob);
            }
#pragma unroll
            for (int i = 0; i < 4; i++)
#pragma unroll
                for (int j = 0; j < 4; j++) {
                    acc[i][j] = __builtin_amdgcn_mfma_f32_16x16x32_bf16(ah[i], bh[j], acc[i][j], 0, 0, 0);
                    acc[i][j] = __builtin_amdgcn_mfma_f32_16x16x32_bf16(ah[i], bl[j], acc[i][j], 0, 0, 0);
                    acc[i][j] = __builtin_amdgcn_mfma_f32_16x16x32_bf16(al[i], bh[j], acc[i][j], 0, 0, 0);
                }
        }
        if (tk + 1 < nk) {
            const int nb = buf ^ 1;
            cvt_store16(lds[nb][0], lds[nb][1], pa0, pa1, off0);
            cvt_store16(lds[nb][0], lds[nb][1], pa2, pa3, off1);
            cvt_store16(lds[nb][2], lds[nb][3], pb0, pb1, off0);
            cvt_store16(lds[nb][2], lds[nb][3], pb2, pb3, off1);
        }
        __syncthreads();
        buf ^= 1;
    }

#pragma unroll
    for (int i = 0; i < 4; i++) {
        const int mrow = m0 + wm + i * 16 + kq * 4;
#pragma unroll
        for (int j = 0; j < 4; j++) {
            const int n = n0 + wn + j * 16 + rl;
            if (n >= N) continue;
#pragma unroll
            for (int rj = 0; rj < 4; rj++) {
                const int m = mrow + rj;
                float c = acc[i][j][rj];
                if (EPI == 0) {
                    C[(size_t)m * ldc + n] = c;
                } else if (EPI == 1) {
                    float v = c + bias[n];
                    C[(size_t)m * ldc + n] = (v > 20.f) ? v : log1pf(expf(v));
                } else {
                    C[(size_t)m * ldc + n] = c + resid[(size_t)m * ldc + n];
                }
            }
        }
    }
}

// ---------------------------------------------------------------- causal depthwise conv(4) + SiLU
__global__ __launch_bounds__(256) void conv_silu_k(const float* __restrict__ xz,
                                                   const float* __restrict__ cw,
                                                   const float* __restrict__ cb,
                                                   float* __restrict__ xc) {
    int idx = blockIdx.x * 256 + threadIdx.x;
    int d = idx & (D_INNER - 1);
    int l = idx >> 11;
    float acc = cb[d];
#pragma unroll
    for (int k = 0; k < 4; k++) {
        int ls = l + k - 3;
        if (ls >= 0) acc += xz[(size_t)ls * (2 * D_INNER) + d] * cw[d * 4 + k];
    }
    acc = acc / (1.0f + expf(-acc));
    xc[(size_t)l * D_INNER + d] = acc;
}

// ---------------------------------------------------------------- chunked selective scan
__global__ __launch_bounds__(256) void scan_p1(const float* __restrict__ dt,
                                               const float* __restrict__ xdbl,
                                               const float* __restrict__ xc,
                                               const float* __restrict__ A_log,
                                               float* __restrict__ Pbuf,
                                               float* __restrict__ Hbuf) {
    int t = threadIdx.x;
    int n = t & 15;
    int d = blockIdx.x * 16 + (t >> 4);
    int ch = blockIdx.y;
    int l0 = ch * LC;
    float Ac = -expf(A_log[d * D_STATE + n]);
    float h = 0.f, P = 1.f;
#pragma unroll 4
    for (int i = 0; i < LC; i++) {
        int l = l0 + i;
        float dtv = dt[(size_t)l * D_INNER + d];
        float xcv = xc[(size_t)l * D_INNER + d];
        float Bv  = xdbl[(size_t)l * NXP + DT_RANK + n];
        float a = expf(dtv * Ac);
        h = a * h + dtv * Bv * xcv;
        P *= a;
    }
    int idx = ch * (D_INNER * D_STATE) + d * D_STATE + n;
    Pbuf[idx] = P;
    Hbuf[idx] = h;
}

__global__ __launch_bounds__(256) void scan_p2(const float* __restrict__ Pbuf,
                                               const float* __restrict__ Hbuf,
                                               float* __restrict__ HSbuf) {
    int tid = blockIdx.x * 256 + threadIdx.x;
    float hs = 0.f;
#pragma unroll
    for (int ch = 0; ch < NC; ch++) {
        int idx = ch * (D_INNER * D_STATE) + tid;
        HSbuf[idx] = hs;
        hs = Pbuf[idx] * hs + Hbuf[idx];
    }
}

__global__ __launch_bounds__(256) void scan_p3(const float* __restrict__ dt,
                                               const float* __restrict__ xdbl,
                                               const float* __restrict__ xc,
                                               const float* __restrict__ xz,
                                               const float* __restrict__ A_log,
                                               const float* __restrict__ D_skip,
                                               const float* __restrict__ HSbuf,
                                               float* __restrict__ y) {
    int t = threadIdx.x;
    int n = t & 15;
    int d = blockIdx.x * 16 + (t >> 4);
    int ch = blockIdx.y;
    int l0 = ch * LC;
    float Ac = -expf(A_log[d * D_STATE + n]);
    float dsk = D_skip[d];
    float h = HSbuf[ch * (D_INNER * D_STATE) + d * D_STATE + n];
    for (int i = 0; i < LC; i++) {
        int l = l0 + i;
        float dtv = dt[(size_t)l * D_INNER + d];
        float xcv = xc[(size_t)l * D_INNER + d];
        float Bv  = xdbl[(size_t)l * NXP + DT_RANK + n];
        float Cv  = xdbl[(size_t)l * NXP + DT_RANK + D_STATE + n];
        float a = expf(dtv * Ac);
        h = a * h + dtv * Bv * xcv;
        float p = h * Cv;
#pragma unroll
        for (int off = 8; off; off >>= 1) p += __shfl_xor(p, off, 16);
        if (n == 0) {
            float zv = xz[(size_t)l * (2 * D_INNER) + D_INNER + d];
            float yv = (p + dsk * xcv) * (zv / (1.0f + expf(-zv)));
            y[(size_t)l * D_INNER + d] = yv;
        }
    }
}

// ---------------------------------------------------------------- launch
extern "C" void kernel_launch(void* const* d_in, const int* in_sizes, int n_in,
                              void* d_out, int out_size, void* d_ws, size_t ws_size,
                              hipStream_t stream) {
    const int*   ids       = (const int*)d_in[0];
    const float* emb       = (const float*)d_in[1];
    const float* ln_g      = (const float*)d_in[2];
    const float* ln_b      = (const float*)d_in[3];
    const float* in_proj_w = (const float*)d_in[4];
    const float* conv_w    = (const float*)d_in[5];
    const float* conv_b    = (const float*)d_in[6];
    const float* x_proj_w  = (const float*)d_in[7];
    const float* dt_proj_w = (const float*)d_in[8];
    const float* dt_proj_b = (const float*)d_in[9];
    const float* A_log     = (const float*)d_in[10];
    const float* D_skip    = (const float*)d_in[11];
    const float* out_proj_w= (const float*)d_in[12];
    const float* lnf_g     = (const float*)d_in[13];
    const float* lnf_b     = (const float*)d_in[14];
    const float* head_w    = (const float*)d_in[15];
    float* out = (float*)d_out;

    // base f32 workspace (88.75 MB)
    float* ws   = (float*)d_ws;
    float* x    = ws;
    float* hy   = x    + (size_t)SEQL * D_MODEL;
    float* xz   = hy   + (size_t)SEQL * D_INNER;
    float* xc   = xz   + (size_t)SEQL * 2 * D_INNER;
    float* xdbl = xc   + (size_t)SEQL * D_INNER;
    float* dt   = xdbl + (size_t)SEQL * NXP;
    float* baseEnd = dt + (size_t)SEQL * D_INNER;
    size_t baseBytes = (size_t)((char*)baseEnd - (char*)ws);

    // bf16 conversion scratch: A (act) needs 16.78 MB; B (weight) needs >= 16.78 MB.
    const size_t ABF_BYTES = (size_t)2048 * 2048 * 2 * 2;   // hi+lo, max activation
    const size_t B_MIN     = (size_t)4096 * 1024 * 4;       // in_proj hi+lo
    short* abf; short* bbf; size_t bcap; bool preHead;
    if (ws_size >= baseBytes + ABF_BYTES + B_MIN) {
        abf  = (short*)((char*)d_ws + baseBytes);
        bbf  = (short*)((char*)abf + ABF_BYTES);
        bcap = ws_size - baseBytes - ABF_BYTES;
        preHead = true;
    } else {
        // scratch in `out` (dead until head GEMM); head falls back to in-loop cvt
        abf  = (short*)out;
        bbf  = (short*)((char*)out + ABF_BYTES);
        bcap = B_MIN;
        preHead = false;
    }
    // scan scratch high in `out` (12.6 MB at +236 MB; out = 262 MB)
    float* Pbuf  = out + (size_t)59000000;
    float* Hbuf  = Pbuf + (size_t)NC * D_INNER * D_STATE;
    float* HSbuf = Hbuf + (size_t)NC * D_INNER * D_STATE;

    // pre-converted GEMM helper: A [2048 x K] (lda=Ald), B [Brows x K] contiguous
    auto preGemm = [&](int epi, const float* A, int Ald, int K, const float* B, int Brows,
                       float* C, int ldc, int Nvalid, const float* bias, const float* resid) {
        int nkt = K >> 5;
        int nbB = (Brows + 127) >> 7;
        short* alo = abf + (size_t)2048 * K;
        short* blo = bbf + (size_t)nbB * 128 * K;
        cvt_k<<<dim3(nkt, 16),  256, 0, stream>>>(A, Ald, 2048, abf, alo);
        cvt_k<<<dim3(nkt, nbB), 256, 0, stream>>>(B, K, Brows, bbf, blo);
        dim3 gg(16, nbB);
        if (epi == 0)      gemm_pre<0><<<gg, 256, 0, stream>>>(abf, alo, bbf, blo, C, ldc, Nvalid, K, bias, resid);
        else if (epi == 1) gemm_pre<1><<<gg, 256, 0, stream>>>(abf, alo, bbf, blo, C, ldc, Nvalid, K, bias, resid);
        else               gemm_pre<2><<<gg, 256, 0, stream>>>(abf, alo, bbf, blo, C, ldc, Nvalid, K, bias, resid);
    };

    embed_k<<<SEQL, 256, 0, stream>>>(ids, emb, x);

    for (int layer = 0; layer < NLAYERS; layer++) {
        ln_k<<<SEQL, 256, 0, stream>>>(x, ln_g + layer * D_MODEL, ln_b + layer * D_MODEL, hy);

        preGemm(0, hy, D_MODEL, D_MODEL,
                in_proj_w + (size_t)layer * 2 * D_INNER * D_MODEL, 2 * D_INNER,
                xz, 2 * D_INNER, 2 * D_INNER, nullptr, nullptr);

        conv_silu_k<<<(SEQL * D_INNER) / 256, 256, 0, stream>>>(
            xz, conv_w + (size_t)layer * D_INNER * 4, conv_b + (size_t)layer * D_INNER, xc);

        preGemm(0, xc, D_INNER, D_INNER,
                x_proj_w + (size_t)layer * NXP * D_INNER, NXP,
                xdbl, NXP, NXP, nullptr, nullptr);

        preGemm(1, xdbl, NXP, DT_RANK,
                dt_proj_w + (size_t)layer * D_INNER * DT_RANK, D_INNER,
                dt, D_INNER, D_INNER, dt_proj_b + (size_t)layer * D_INNER, nullptr);

        dim3 gs(D_INNER / 16, NC);
        scan_p1<<<gs, 256, 0, stream>>>(dt, xdbl, xc,
                                        A_log + (size_t)layer * D_INNER * D_STATE, Pbuf, Hbuf);
        scan_p2<<<(D_INNER * D_STATE) / 256, 256, 0, stream>>>(Pbuf, Hbuf, HSbuf);
        scan_p3<<<gs, 256, 0, stream>>>(dt, xdbl, xc, xz,
                                        A_log + (size_t)layer * D_INNER * D_STATE,
                                        D_skip + (size_t)layer * D_INNER, HSbuf, hy);

        preGemm(2, hy, D_INNER, D_INNER,
                out_proj_w + (size_t)layer * D_MODEL * D_INNER, D_MODEL,
                x, D_MODEL, D_MODEL, nullptr, x);
    }

    ln_k<<<SEQL, 256, 0, stream>>>(x, lnf_g, lnf_b, hy);

    if (preHead) {
        // convert A (final LN out) once; stripe head_w conversion through bbf capacity
        short* alo = abf + (size_t)2048 * D_MODEL;
        cvt_k<<<dim3(D_MODEL / 32, 16), 256, 0, stream>>>(hy, D_MODEL, 2048, abf, alo);
        size_t bytesPerRow = (size_t)D_MODEL * 2 * 2;                 // hi+lo
        int rowsCap = (int)((bcap / bytesPerRow) & ~(size_t)127);
        if (rowsCap > VOCAB) rowsCap = VOCAB;
        for (int r0 = 0; r0 < VOCAB; r0 += rowsCap) {
            int rows = VOCAB - r0; if (rows > rowsCap) rows = rowsCap;
            int nb = rows >> 7;
            short* blo = bbf + (size_t)rows * D_MODEL;
            cvt_k<<<dim3(D_MODEL / 32, nb), 256, 0, stream>>>(head_w + (size_t)r0 * D_MODEL, D_MODEL, rows, bbf, blo);
            gemm_pre<0><<<dim3(16, nb), 256, 0, stream>>>(abf, alo, bbf, blo,
                                                          out + r0, VOCAB, rows, D_MODEL,
                                                          nullptr, nullptr);
        }
    } else {
        dim3 g5(SEQL / 128, VOCAB / 128);
        gemm_mfma<0><<<g5, 256, 0, stream>>>(hy, D_MODEL, head_w, D_MODEL,
                                             out, VOCAB, SEQL, VOCAB, D_MODEL,
                                             nullptr, nullptr);
    }
}